// Round 1
// 421.158 us; speedup vs baseline: 1.0994x; 1.0994x over previous
//
#include <hip/hip_runtime.h>

#define NN 50000
#define NE 800000

typedef __attribute__((ext_vector_type(8))) short bf16x8;
typedef __attribute__((ext_vector_type(8))) unsigned short us8;
typedef __attribute__((ext_vector_type(4))) unsigned short us4;
typedef __attribute__((ext_vector_type(4))) float f32x4;

#define MFMA16 __builtin_amdgcn_mfma_f32_16x16x32_bf16

__device__ __forceinline__ unsigned short f2b(float f) {
    union { float f; unsigned int u; } x; x.f = f;
    unsigned int r = x.u + 0x7FFFu + ((x.u >> 16) & 1u);
    return (unsigned short)(r >> 16);
}

// packed bf16x2 atomic add (gfx90a+/gfx950 native, memory-side RMW, fire-and-forget)
__device__ __forceinline__ void atomic_pk_add_bf16(unsigned short* addr, unsigned int pk) {
    asm volatile("global_atomic_pk_add_bf16 %0, %1, off" :: "v"(addr), "v"(pk) : "memory");
}

// ---------------- prep: convert nodes to bf16; convert+transpose weights ----------------
__global__ __launch_bounds__(256) void prep_kernel(
    const float* __restrict__ nodes,
    const float* __restrict__ We1, const float* __restrict__ We2,
    const float* __restrict__ Wn1, const float* __restrict__ Wn2,
    unsigned short* __restrict__ nodes_bf,
    unsigned short* __restrict__ We1T, unsigned short* __restrict__ We2T,
    unsigned short* __restrict__ Wn1T, unsigned short* __restrict__ Wn2T)
{
    const int b = blockIdx.x, t = threadIdx.x;
    if (b < 400) {
        const float4* src = (const float4*)nodes;
        for (int i = b * 256 + t; i < NN * 16; i += 400 * 256) {
            float4 v = src[i];
            us4 o; o[0] = f2b(v.x); o[1] = f2b(v.y); o[2] = f2b(v.z); o[3] = f2b(v.w);
            *(us4*)&nodes_bf[(size_t)i * 4] = o;
        }
    } else {
        const int base = (b - 400) * 256 + t;
        for (int idx = base; idx < 57344; idx += 16 * 256) {
            if (idx < 24576) {               // We1T[128][192] <- We1[192][128]
                int n = idx / 192, k = idx % 192;
                We1T[idx] = f2b(We1[k * 128 + n]);
            } else if (idx < 32768) {        // We2T[64][128] <- We2[128][64]
                int j = idx - 24576; int n = j / 128, k = j % 128;
                We2T[j] = f2b(We2[k * 64 + n]);
            } else if (idx < 49152) {        // Wn1T[128][128] <- Wn1[128][128]
                int j = idx - 32768; int n = j / 128, k = j % 128;
                Wn1T[j] = f2b(Wn1[k * 128 + n]);
            } else {                         // Wn2T[64][128] <- Wn2[128][64]
                int j = idx - 49152; int n = j / 128, k = j % 128;
                Wn2T[j] = f2b(Wn2[k * 64 + n]);
            }
        }
    }
}

// ---------------- edge kernel: 64 edges/block, 4 waves, MFMA ----------------
// xs[64][200] bf16 gathered input (192 valid); hs aliases xs with stride 136.
// wbT[n][40] weight chunk, transposed, 32 valid k per chunk.
__global__ __launch_bounds__(256, 4) void edge_kernel(
    const unsigned short* __restrict__ nodes_bf, const float* __restrict__ edges,
    const unsigned short* __restrict__ We1T, const float* __restrict__ be1,
    const unsigned short* __restrict__ We2T, const float* __restrict__ be2,
    const int* __restrict__ senders, const int* __restrict__ receivers,
    unsigned short* __restrict__ agg_bf)
{
    __shared__ unsigned short xs[64 * 200];   // 25.6 KB (hs aliases: stride 136; f32 stage aliases)
    __shared__ unsigned short wb[128 * 40];   // 10.0 KB
    __shared__ int ridx[64];
    __shared__ int sidx[64];

    const int t = threadIdx.x;
    const int e0 = blockIdx.x * 64;
    const int w = t >> 6;        // wave 0..3
    const int l = t & 63;
    const int lc = l & 15;       // lane col
    const int lq = l >> 4;       // quad

    if (t < 64) { ridx[t] = receivers[e0 + t]; sidx[t] = senders[e0 + t]; }
    __syncthreads();

    // gather edges (fp32 -> bf16)
    #pragma unroll
    for (int i = 0; i < 4; ++i) {
        int idx = t + 256 * i;            // 0..1023
        int m = idx >> 4, q = idx & 15;
        float4 v = *(const float4*)&edges[((size_t)(e0 + m)) * 64 + q * 4];
        us4 o; o[0] = f2b(v.x); o[1] = f2b(v.y); o[2] = f2b(v.z); o[3] = f2b(v.w);
        *(us4*)&xs[m * 200 + q * 4] = o;
    }
    // gather receiver node feats (bf16 copy)
    #pragma unroll
    for (int i = 0; i < 2; ++i) {
        int idx = t + 256 * i;            // 0..511
        int m = idx >> 3, q = idx & 7;
        us8 v = *(const us8*)&nodes_bf[(size_t)ridx[m] * 64 + q * 8];
        *(us8*)&xs[m * 200 + 64 + q * 8] = v;
    }
    // gather sender node feats
    #pragma unroll
    for (int i = 0; i < 2; ++i) {
        int idx = t + 256 * i;
        int m = idx >> 3, q = idx & 7;
        us8 v = *(const us8*)&nodes_bf[(size_t)sidx[m] * 64 + q * 8];
        *(us8*)&xs[m * 200 + 128 + q * 8] = v;
    }
    __syncthreads();

    // GEMM1: [64,192] @ We1[192,128]; wave w -> N cols [w*32, w*32+32), all 4 M tiles
    f32x4 acc[4][2];
    #pragma unroll
    for (int mt = 0; mt < 4; ++mt) { acc[mt][0] = (f32x4)0.f; acc[mt][1] = (f32x4)0.f; }

    for (int c = 0; c < 6; ++c) {
        const int k0 = 32 * c;
        #pragma unroll
        for (int i = 0; i < 2; ++i) {
            int idx = t + 256 * i;        // 0..511
            int n = idx >> 2, cc = idx & 3;
            *(us8*)&wb[n * 40 + cc * 8] = *(const us8*)&We1T[n * 192 + k0 + cc * 8];
        }
        __syncthreads();
        bf16x8 b0 = *(const bf16x8*)&wb[(w * 32 + lc) * 40 + lq * 8];
        bf16x8 b1 = *(const bf16x8*)&wb[(w * 32 + 16 + lc) * 40 + lq * 8];
        #pragma unroll
        for (int mt = 0; mt < 4; ++mt) {
            bf16x8 a = *(const bf16x8*)&xs[(mt * 16 + lc) * 200 + k0 + lq * 8];
            acc[mt][0] = MFMA16(a, b0, acc[mt][0], 0, 0, 0);
            acc[mt][1] = MFMA16(a, b1, acc[mt][1], 0, 0, 0);
        }
        __syncthreads();
    }

    // bias + relu -> hs (aliases xs, stride 136)
    #pragma unroll
    for (int nt = 0; nt < 2; ++nt) {
        int col = w * 32 + nt * 16 + lc;
        float bias = be1[col];
        #pragma unroll
        for (int mt = 0; mt < 4; ++mt) {
            #pragma unroll
            for (int r = 0; r < 4; ++r) {
                int row = mt * 16 + lq * 4 + r;
                float v = fmaxf(acc[mt][nt][r] + bias, 0.f);
                xs[row * 136 + col] = f2b(v);
            }
        }
    }
    __syncthreads();

    // GEMM2: [64,128] @ We2[128,64]; wave w -> N cols [w*16, w*16+16)
    f32x4 acc2[4];
    #pragma unroll
    for (int mt = 0; mt < 4; ++mt) acc2[mt] = (f32x4)0.f;

    for (int c = 0; c < 4; ++c) {
        const int k0 = 32 * c;
        {
            int n = t >> 2, cc = t & 3;   // 64 rows x 4 chunks
            *(us8*)&wb[n * 40 + cc * 8] = *(const us8*)&We2T[n * 128 + k0 + cc * 8];
        }
        __syncthreads();
        bf16x8 b = *(const bf16x8*)&wb[(w * 16 + lc) * 40 + lq * 8];
        #pragma unroll
        for (int mt = 0; mt < 4; ++mt) {
            bf16x8 a = *(const bf16x8*)&xs[(mt * 16 + lc) * 136 + k0 + lq * 8];
            acc2[mt] = MFMA16(a, b, acc2[mt], 0, 0, 0);
        }
        __syncthreads();
    }

    // stage acc2+bias into LDS f32 [64][66] (stride 66 -> ~conflict-free)
    float* fs = (float*)xs;               // 64*66*4 = 16896 B, fits in xs
    {
        const int col = w * 16 + lc;
        const float bias2 = be2[col];
        #pragma unroll
        for (int mt = 0; mt < 4; ++mt) {
            #pragma unroll
            for (int r = 0; r < 4; ++r) {
                int row = mt * 16 + lq * 4 + r;
                fs[row * 66 + col] = acc2[mt][r] + bias2;
            }
        }
    }
    __syncthreads();

    // packed bf16x2 scatter-add: 2048 pairs, 8 per thread.
    // lanes 0..31 cover one agg row's 128B line -> good line locality per wave.
    #pragma unroll
    for (int i = 0; i < 8; ++i) {
        int p = t + 256 * i;
        int row = p >> 5, cp = p & 31;
        float2 v = *(const float2*)&fs[row * 66 + cp * 2];
        unsigned int pk = (unsigned int)f2b(v.x) | ((unsigned int)f2b(v.y) << 16);
        atomic_pk_add_bf16(&agg_bf[(size_t)ridx[row] * 64 + cp * 2], pk);
    }
}

// ---------------- node kernel: 64 nodes/block, 4 waves, MFMA ----------------
__global__ __launch_bounds__(256, 4) void node_kernel(
    const unsigned short* __restrict__ nodes_bf, const unsigned short* __restrict__ agg_bf,
    const unsigned short* __restrict__ Wn1T, const float* __restrict__ bn1,
    const unsigned short* __restrict__ Wn2T, const float* __restrict__ bn2,
    float* __restrict__ out)
{
    __shared__ unsigned short xs[64 * 136];   // input [agg|node] and hs (both stride 136)
    __shared__ unsigned short wb[128 * 40];

    const int t = threadIdx.x;
    const int n0 = blockIdx.x * 64;
    const int w = t >> 6;
    const int l = t & 63;
    const int lc = l & 15;
    const int lq = l >> 4;

    // stage agg (bf16 copy), cols 0..63
    #pragma unroll
    for (int i = 0; i < 2; ++i) {
        int idx = t + 256 * i;
        int m = idx >> 3, q = idx & 7;
        int n = n0 + m;
        us8 v = {0, 0, 0, 0, 0, 0, 0, 0};
        if (n < NN) v = *(const us8*)&agg_bf[(size_t)n * 64 + q * 8];
        *(us8*)&xs[m * 136 + q * 8] = v;
    }
    // stage node feats (bf16), cols 64..127
    #pragma unroll
    for (int i = 0; i < 2; ++i) {
        int idx = t + 256 * i;
        int m = idx >> 3, q = idx & 7;
        int n = n0 + m;
        us8 v = {0, 0, 0, 0, 0, 0, 0, 0};
        if (n < NN) v = *(const us8*)&nodes_bf[(size_t)n * 64 + q * 8];
        *(us8*)&xs[m * 136 + 64 + q * 8] = v;
    }
    __syncthreads();

    // GEMM1: [64,128] @ Wn1[128,128]
    f32x4 acc[4][2];
    #pragma unroll
    for (int mt = 0; mt < 4; ++mt) { acc[mt][0] = (f32x4)0.f; acc[mt][1] = (f32x4)0.f; }

    for (int c = 0; c < 4; ++c) {
        const int k0 = 32 * c;
        #pragma unroll
        for (int i = 0; i < 2; ++i) {
            int idx = t + 256 * i;
            int n = idx >> 2, cc = idx & 3;
            *(us8*)&wb[n * 40 + cc * 8] = *(const us8*)&Wn1T[n * 128 + k0 + cc * 8];
        }
        __syncthreads();
        bf16x8 b0 = *(const bf16x8*)&wb[(w * 32 + lc) * 40 + lq * 8];
        bf16x8 b1 = *(const bf16x8*)&wb[(w * 32 + 16 + lc) * 40 + lq * 8];
        #pragma unroll
        for (int mt = 0; mt < 4; ++mt) {
            bf16x8 a = *(const bf16x8*)&xs[(mt * 16 + lc) * 136 + k0 + lq * 8];
            acc[mt][0] = MFMA16(a, b0, acc[mt][0], 0, 0, 0);
            acc[mt][1] = MFMA16(a, b1, acc[mt][1], 0, 0, 0);
        }
        __syncthreads();
    }

    // bias + relu -> hs (same region, stride 136)
    #pragma unroll
    for (int nt = 0; nt < 2; ++nt) {
        int col = w * 32 + nt * 16 + lc;
        float bias = bn1[col];
        #pragma unroll
        for (int mt = 0; mt < 4; ++mt) {
            #pragma unroll
            for (int r = 0; r < 4; ++r) {
                int row = mt * 16 + lq * 4 + r;
                float v = fmaxf(acc[mt][nt][r] + bias, 0.f);
                xs[row * 136 + col] = f2b(v);
            }
        }
    }
    __syncthreads();

    // GEMM2: [64,128] @ Wn2[128,64]
    f32x4 acc2[4];
    #pragma unroll
    for (int mt = 0; mt < 4; ++mt) acc2[mt] = (f32x4)0.f;

    for (int c = 0; c < 4; ++c) {
        const int k0 = 32 * c;
        {
            int n = t >> 2, cc = t & 3;
            *(us8*)&wb[n * 40 + cc * 8] = *(const us8*)&Wn2T[n * 128 + k0 + cc * 8];
        }
        __syncthreads();
        bf16x8 b = *(const bf16x8*)&wb[(w * 16 + lc) * 40 + lq * 8];
        #pragma unroll
        for (int mt = 0; mt < 4; ++mt) {
            bf16x8 a = *(const bf16x8*)&xs[(mt * 16 + lc) * 136 + k0 + lq * 8];
            acc2[mt] = MFMA16(a, b, acc2[mt], 0, 0, 0);
        }
        __syncthreads();
    }

    const int col = w * 16 + lc;
    const float bias2 = bn2[col];
    #pragma unroll
    for (int mt = 0; mt < 4; ++mt) {
        #pragma unroll
        for (int r = 0; r < 4; ++r) {
            int row = mt * 16 + lq * 4 + r;
            int n = n0 + row;
            if (n < NN) out[(size_t)n * 64 + col] = acc2[mt][r] + bias2;
        }
    }
}

extern "C" void kernel_launch(void* const* d_in, const int* in_sizes, int n_in,
                              void* d_out, int out_size, void* d_ws, size_t ws_size,
                              hipStream_t stream) {
    const float* nodes = (const float*)d_in[0];
    const float* edges = (const float*)d_in[1];
    const float* We1   = (const float*)d_in[2];
    const float* be1   = (const float*)d_in[3];
    const float* We2   = (const float*)d_in[4];
    const float* be2   = (const float*)d_in[5];
    const float* Wn1   = (const float*)d_in[6];
    const float* bn1   = (const float*)d_in[7];
    const float* Wn2   = (const float*)d_in[8];
    const float* bn2   = (const float*)d_in[9];
    const int* senders   = (const int*)d_in[10];
    const int* receivers = (const int*)d_in[11];
    float* out = (float*)d_out;

    // ws layout (bytes) — keep total footprint identical to the proven 19.3 MB layout
    char* ws = (char*)d_ws;
    unsigned short* agg_bf = (unsigned short*)ws;                //  6,400,000 B (bf16 now)
    unsigned short* nodes_bf = (unsigned short*)(ws + 12800000); //  6,400,000 B
    unsigned short* We1T = (unsigned short*)(ws + 19200000);     //     49,152 B
    unsigned short* We2T = (unsigned short*)(ws + 19249152);     //     16,384 B
    unsigned short* Wn1T = (unsigned short*)(ws + 19265536);     //     32,768 B
    unsigned short* Wn2T = (unsigned short*)(ws + 19298304);     //     16,384 B

    hipMemsetAsync(agg_bf, 0, (size_t)NN * 64 * sizeof(unsigned short), stream);
    prep_kernel<<<416, 256, 0, stream>>>(nodes, We1, We2, Wn1, Wn2,
                                         nodes_bf, We1T, We2T, Wn1T, Wn2T);
    edge_kernel<<<NE / 64, 256, 0, stream>>>(nodes_bf, edges, We1T, be1, We2T, be2,
                                             senders, receivers, agg_bf);
    node_kernel<<<(NN + 63) / 64, 256, 0, stream>>>(nodes_bf, agg_bf, Wn1T, bn1, Wn2T, bn2, out);
}